// Round 3
// baseline (3541.087 us; speedup 1.0000x reference)
//
#include <hip/hip_runtime.h>
#include <hip/hip_bf16.h>
#include <stdint.h>

typedef unsigned short u16;

#define NB  32
#define NT  4096
#define NDZ 128
#define NG  384   // 3*DZ
#define NIN 192   // IN_DIM

// ---------- helpers ----------
__device__ __forceinline__ float rlane(float v, int k) {
  return __int_as_float(__builtin_amdgcn_readlane(__float_as_int(v), k));
}
__device__ __forceinline__ float fast_rcp(float x) { return __builtin_amdgcn_rcpf(x); }
__device__ __forceinline__ float sigmoid_f(float x) { return fast_rcp(1.f + __expf(-x)); }
__device__ __forceinline__ float tanh_f(float x) {
  return 1.f - 2.f * fast_rcp(1.f + __expf(2.f * x));
}
__device__ __forceinline__ u16 f2bf(float f) {
  unsigned u = __float_as_uint(f);
  return (u16)((u + 0x7fffu + ((u >> 16) & 1u)) >> 16);
}
__device__ __forceinline__ float bf2f(u16 u) { return __uint_as_float((unsigned)u << 16); }

// LDS-only barrier (ds ops drained via lgkmcnt; vmcnt stays in flight so the
// t+2 gi prefetch and traj stores cross barriers without draining).
__device__ __forceinline__ void bar_lds() {
  asm volatile("s_waitcnt lgkmcnt(0)\n\ts_barrier" ::: "memory");
}

// gi workspace: bf16 validated (absmax 3.9e-3 << 5.9e-2); f32 if ws allows
__device__ __forceinline__ float giload(const float* p) { return *p; }
__device__ __forceinline__ float giload(const u16* p)   { return bf2f(*p); }
__device__ __forceinline__ void store8(float* p, const float* v) {
  float4 a = {v[0], v[1], v[2], v[3]}, b = {v[4], v[5], v[6], v[7]};
  *(float4*)p = a; *(float4*)(p + 4) = b;
}
__device__ __forceinline__ void store8(u16* p, const float* v) {
  uint4 o;
  o.x = (unsigned)f2bf(v[0]) | ((unsigned)f2bf(v[1]) << 16);
  o.y = (unsigned)f2bf(v[2]) | ((unsigned)f2bf(v[3]) << 16);
  o.z = (unsigned)f2bf(v[4]) | ((unsigned)f2bf(v[5]) << 16);
  o.w = (unsigned)f2bf(v[6]) | ((unsigned)f2bf(v[7]) << 16);
  *(uint4*)p = o;
}

// ---------- Phase 1: gi = x @ W_ih^T + b_ih (unchanged) ----------
#define GM 128
#define GN 128
#define LDSS 132

template <typename GT>
__global__ __launch_bounds__(256) void gemm_gi(
    const float* __restrict__ Y, const float* __restrict__ M,
    const float* __restrict__ H, const float* __restrict__ Wih,
    const float* __restrict__ bih, GT* __restrict__ gi)
{
  __shared__ float As[32 * LDSS];
  __shared__ float Bs[32 * LDSS];
  const int tid = threadIdx.x;
  const size_t m0 = (size_t)blockIdx.x * GM;
  const int n0 = blockIdx.y * GN;
  const int tm = tid & 15;
  const int tn = tid >> 4;

  float acc[8][8];
#pragma unroll
  for (int i = 0; i < 8; ++i)
#pragma unroll
    for (int j = 0; j < 8; ++j) acc[i][j] = 0.f;

#pragma unroll
  for (int kc = 0; kc < 6; ++kc) {
    const float* src; int stride; int off;
    if (kc == 0)      { src = Y; stride = 32;  off = 0; }
    else if (kc == 1) { src = M; stride = 32;  off = 0; }
    else              { src = H; stride = 128; off = (kc - 2) * 32; }
#pragma unroll
    for (int it = 0; it < 4; ++it) {
      int x = tid + it * 256;
      int row = x >> 3, q = x & 7;
      float4 v = *(const float4*)(src + (m0 + (size_t)row) * stride + off + q * 4);
      As[(q * 4 + 0) * LDSS + row] = v.x;
      As[(q * 4 + 1) * LDSS + row] = v.y;
      As[(q * 4 + 2) * LDSS + row] = v.z;
      As[(q * 4 + 3) * LDSS + row] = v.w;
    }
#pragma unroll
    for (int it = 0; it < 4; ++it) {
      int x = tid + it * 256;
      int g = x >> 3, q = x & 7;
      float4 v = *(const float4*)(Wih + (size_t)(n0 + g) * NIN + kc * 32 + q * 4);
      Bs[(q * 4 + 0) * LDSS + g] = v.x;
      Bs[(q * 4 + 1) * LDSS + g] = v.y;
      Bs[(q * 4 + 2) * LDSS + g] = v.z;
      Bs[(q * 4 + 3) * LDSS + g] = v.w;
    }
    __syncthreads();
#pragma unroll
    for (int kk = 0; kk < 32; ++kk) {
      float4 a0 = *(const float4*)&As[kk * LDSS + tm * 8];
      float4 a1 = *(const float4*)&As[kk * LDSS + tm * 8 + 4];
      float4 b0 = *(const float4*)&Bs[kk * LDSS + tn * 8];
      float4 b1 = *(const float4*)&Bs[kk * LDSS + tn * 8 + 4];
      float av[8] = {a0.x, a0.y, a0.z, a0.w, a1.x, a1.y, a1.z, a1.w};
      float bv[8] = {b0.x, b0.y, b0.z, b0.w, b1.x, b1.y, b1.z, b1.w};
#pragma unroll
      for (int i = 0; i < 8; ++i)
#pragma unroll
        for (int j = 0; j < 8; ++j)
          acc[i][j] = __builtin_fmaf(av[i], bv[j], acc[i][j]);
    }
    __syncthreads();
  }
  float bv[8];
#pragma unroll
  for (int j = 0; j < 8; ++j) bv[j] = bih[n0 + tn * 8 + j];
#pragma unroll
  for (int i = 0; i < 8; ++i) {
    size_t row = m0 + (size_t)(tm * 8 + i);
    GT* o = gi + row * NG + n0 + tn * 8;
    float v[8];
#pragma unroll
    for (int j = 0; j < 8; ++j) v[j] = acc[i][j] + bv[j];
    store8(o, v);
  }
}

// ---------- Phase 2: scan, 4 waves, minimal LDS-pipe traffic ----------
// DS pipe is per-CU (shared by 4 SIMDs); R1's 8-wave version issued 128 ds
// ops/step (~740+ cyc serialization + 3-way read conflicts, the measured
// stall). Partial-exchange volume scales with wave count, so: 4 waves,
// wave w owns K-slice AND gate elems [32w,32w+32).
//   lane e = lane&31 <-> elem j = 32w+e; hi = lane>>5 mirrors.
// Per step per wave: 6 ds_write + 6 ds_read + 2 bpermute = 56 ds ops/CU
// (was 128), all bank-conflict-free (2 addrs/bank max).
// Gate split: hi=0 reduces r-row, hi=1 reduces u-row (4 reads each);
// each half reduces 2 of 4 n-partials (2 reads); two __shfl(lane^32)
// exchange primary sums + n-halves. Mirror-lane zc/zdr divergence is
// harmless: readlane & stores only consult lanes 0-31.
// P double-buffered -> ONE bar_lds per step (vmcnt never drained).
#define KS 32

template <typename GT>
__global__ __launch_bounds__(256, 1) void scan_k(
    const float* __restrict__ zinit, const float* __restrict__ tdyn,
    const int* __restrict__ lens, const float* __restrict__ Whh,
    const float* __restrict__ bhh, const float* __restrict__ lgam,
    const GT* __restrict__ gi, float* __restrict__ out)
{
  const int b = blockIdx.x;
  const int tid = threadIdx.x;   // 0..255
  const int lane = tid & 63;
  const int w = tid >> 6;        // wave 0..3
  const int k0 = w * KS;
  const int e = lane & 31;
  const int hi = lane >> 5;      // 0: r-primary, 1: u-primary
  const int j = k0 + e;          // owned elem (mirrored in hi lanes)

  __shared__ float P0[4][NG];    // 6 KB
  __shared__ float P1[4][NG];    // 6 KB

  // weights: rows (lane+128p, lane+128p+64), k in [k0,k0+32): 192 VGPRs
  float2 wp[3][KS];
#pragma unroll
  for (int p = 0; p < 3; ++p) {
    const float4* r0 = (const float4*)(Whh + (size_t)(lane + 128 * p) * NDZ + k0);
    const float4* r1 = (const float4*)(Whh + (size_t)(lane + 128 * p + 64) * NDZ + k0);
#pragma unroll
    for (int q = 0; q < 8; ++q) {
      float4 v0 = r0[q];
      float4 v1 = r1[q];
      wp[p][4 * q + 0].x = v0.x; wp[p][4 * q + 0].y = v1.x;
      wp[p][4 * q + 1].x = v0.y; wp[p][4 * q + 1].y = v1.y;
      wp[p][4 * q + 2].x = v0.z; wp[p][4 * q + 2].y = v1.z;
      wp[p][4 * q + 3].x = v0.w; wp[p][4 * q + 3].y = v1.w;
    }
  }

  const int len = lens[b];
  const float* tp = tdyn + (size_t)b * NT;
  const GT* gb = gi + (size_t)b * NT * NG;
  float* traj = out + (size_t)NB * NDZ + (size_t)b * NT * NDZ;

  // per-elem state (mirrored across halves; lanes 0-31 authoritative)
  float zc = zinit[b * NDZ + j];
  const float lg = lgam[j];
  const float gam = (lg > 15.f) ? lg : __logf(1.f + __expf(lg));
  const float br = bhh[j], bu = bhh[NDZ + j], bn = bhh[2 * NDZ + j];
  float t_prev = tp[0];
  float zdr = zc;                // z_d(0) = z0 (dt0 = 0)

  const int prow = hi ? (NDZ + j) : j;  // primary reduce row (r or u)
  const int nrow = 2 * NDZ + j;         // n row
  const int nq = hi * 2;                // this half reduces n partials nq,nq+1

  // prefetch buffers (static names, no runtime index)
  float ptkA = tp[1];
  float ptkB = tp[2];
  float pgrA = giload(gb + j), pguA = giload(gb + NDZ + j), pgnA = giload(gb + 2 * NDZ + j);
  float pgrB = giload(gb + NG + j), pguB = giload(gb + NG + NDZ + j), pgnB = giload(gb + NG + 2 * NDZ + j);

  auto stepf = [&](float (*PB)[NG], float& ptkX, float& pgrX, float& pguX, float& pgnX, int t) {
    const bool active = (t < len);  // block-uniform
    if (active) {
      float2 a0 = {0.f, 0.f}, a1 = {0.f, 0.f}, a2 = {0.f, 0.f};
#pragma unroll
      for (int k = 0; k < KS; ++k) {
        const float zk = rlane(zdr, k);   // z_d[k0+k], produced in-wave last step
        a0.x = __builtin_fmaf(wp[0][k].x, zk, a0.x);
        a0.y = __builtin_fmaf(wp[0][k].y, zk, a0.y);
        a1.x = __builtin_fmaf(wp[1][k].x, zk, a1.x);
        a1.y = __builtin_fmaf(wp[1][k].y, zk, a1.y);
        a2.x = __builtin_fmaf(wp[2][k].x, zk, a2.x);
        a2.y = __builtin_fmaf(wp[2][k].y, zk, a2.y);
      }
      // P[w][row] = partial of output row `row` over K-slice w
      PB[w][lane]       = a0.x;  PB[w][lane + 64]  = a0.y;
      PB[w][lane + 128] = a1.x;  PB[w][lane + 192] = a1.y;
      PB[w][lane + 256] = a2.x;  PB[w][lane + 320] = a2.y;
    }
    bar_lds();  // ONLY barrier of the step: partials published

    const float zd = zdr;
    if (active) {
      const float p0 = PB[0][prow], p1 = PB[1][prow];
      const float p2 = PB[2][prow], p3 = PB[3][prow];
      const float n0 = PB[nq][nrow], n1 = PB[nq + 1][nrow];
      const float prim = (p0 + p1) + (p2 + p3);
      const float n2 = n0 + n1;
      const float oth = __shfl(prim, lane ^ 32, 64);  // swap primary sums
      const float nx  = __shfl(n2,   lane ^ 32, 64);  // swap n halves
      const float snv = n2 + nx;
      const float sr = hi ? oth  : prim;
      const float su = hi ? prim : oth;
      const float r = sigmoid_f(sr + br + pgrX);
      const float u = sigmoid_f(su + bu + pguX);
      const float n = tanh_f(__builtin_fmaf(r, snv + bn, pgnX));
      zc = (1.f - u) * n + u * zd;
    } else {
      zc = zd;
    }
    if (lane < 32) traj[(size_t)t * NDZ + j] = zc;

    // z_d(t+1) = zc * exp(-gam * max(tp[t+1]-tp[t],0)), computed in-wave
    const float tk = ptkX;
    const float dt = fmaxf(tk - t_prev, 0.f);
    zdr = zc * __expf(-gam * dt);
    t_prev = tk;

    // prefetch for step t+2 (clamped; values unused past the end)
    const int t2 = (t + 2 < NT) ? (t + 2) : (NT - 1);
    const int t3 = (t + 3 < NT) ? (t + 3) : (NT - 1);
    ptkX = tp[t3];
    const GT* g2 = gb + (size_t)t2 * NG;
    pgrX = giload(g2 + j);
    pguX = giload(g2 + NDZ + j);
    pgnX = giload(g2 + 2 * NDZ + j);
  };

  for (int t = 0; t < NT; t += 2) {
    stepf(P0, ptkA, pgrA, pguA, pgnA, t);
    stepf(P1, ptkB, pgrB, pguB, pgnB, t + 1);
  }
  if (lane < 32) out[b * NDZ + j] = zc;  // z_final
}

extern "C" void kernel_launch(void* const* d_in, const int* in_sizes, int n_in,
                              void* d_out, int out_size, void* d_ws, size_t ws_size,
                              hipStream_t stream) {
  const float* z0   = (const float*)d_in[0];
  const float* tdyn = (const float*)d_in[1];
  const float* Y    = (const float*)d_in[2];
  const float* M    = (const float*)d_in[3];
  const int*   lens = (const int*)d_in[4];
  const float* H    = (const float*)d_in[5];
  const float* Wih  = (const float*)d_in[6];
  const float* bih  = (const float*)d_in[7];
  const float* Whh  = (const float*)d_in[8];
  const float* bhh  = (const float*)d_in[9];
  const float* lgam = (const float*)d_in[10];
  float* out = (float*)d_out;  // f32: [B*DZ] z_final, then [B*T*DZ] Z_traj

  const size_t needF32 = (size_t)NB * NT * NG * sizeof(float);  // 201.3 MB
  dim3 ggrid((NB * NT) / GM, NG / GN);
  if (ws_size >= needF32) {
    float* gi = (float*)d_ws;
    gemm_gi<float><<<ggrid, 256, 0, stream>>>(Y, M, H, Wih, bih, gi);
    scan_k<float><<<dim3(NB), 256, 0, stream>>>(z0, tdyn, lens, Whh, bhh, lgam, gi, out);
  } else {
    u16* gi = (u16*)d_ws;  // bf16 gi (validated: absmax 3.9e-3)
    gemm_gi<u16><<<ggrid, 256, 0, stream>>>(Y, M, H, Wih, bih, gi);
    scan_k<u16><<<dim3(NB), 256, 0, stream>>>(z0, tdyn, lens, Whh, bhh, lgam, gi, out);
  }
}